// Round 12
// baseline (3048.789 us; speedup 1.0000x reference)
//
#include <hip/hip_runtime.h>
#include <hip/hip_bf16.h>

typedef __bf16 bf16;
typedef __bf16 bf16x8 __attribute__((ext_vector_type(8)));
typedef float f32x4 __attribute__((ext_vector_type(4)));
typedef unsigned int u32x4 __attribute__((ext_vector_type(4)));

#define B_SZ 32
#define T_SZ 64
#define H_SZ 512
#define V_SZ 32000
#define NWG_REC 8
#define NTILES 250
#define MTILES 16

__device__ __forceinline__ float sigmoidf_(float v) { return 1.0f / (1.0f + expf(-v)); }

__device__ __forceinline__ bf16x8 cvt8(const float* __restrict__ p) {
  float4 a = *(const float4*)p;
  float4 b = *(const float4*)(p + 4);
  bf16x8 o;
  o[0] = (bf16)a.x; o[1] = (bf16)a.y; o[2] = (bf16)a.z; o[3] = (bf16)a.w;
  o[4] = (bf16)b.x; o[5] = (bf16)b.y; o[6] = (bf16)b.z; o[7] = (bf16)b.w;
  return o;
}

// ---- LLC-coherent primitives (bypass L1/L2 via sc0 sc1) ----
#define GLD(dst, base, off) \
  asm volatile("global_load_dwordx4 %0, %1, off offset:" off " sc0 sc1" \
               : "=v"(dst) : "v"(base))
#define GST2(base, off, val) do { \
  unsigned int w_ = (unsigned int)__builtin_bit_cast(unsigned short, (bf16)(val)); \
  asm volatile("global_store_short %0, %1, off offset:" off " sc0 sc1" \
               :: "v"(base), "v"(w_) : "memory"); \
} while (0)
#define WAITV  asm volatile("s_waitcnt vmcnt(0)" ::: "memory")
#define SCHEDB __builtin_amdgcn_sched_barrier(0)

__device__ __forceinline__ int llc_poll(const int* p) {
  int r;
  asm volatile("global_load_dword %0, %1, off sc0 sc1\n\ts_waitcnt vmcnt(0)"
               : "=v"(r) : "v"(p) : "memory");
  return r;
}

// ---------------- prep: flags, Wz/Wr/Wh h-part extract+cvt ----------------
__global__ void prep_k(const float* __restrict__ feat, int* __restrict__ ctr,
                       const float* __restrict__ Wz, const float* __restrict__ Wr,
                       const float* __restrict__ Wh, bf16* __restrict__ dst) {
  int i = blockIdx.x * blockDim.x + threadIdx.x;   // 98304 threads
  int w = i >> 15;
  int rem = i & 32767;
  int n = rem >> 6;
  int k8 = (rem & 63) * 8;
  const float* W = (w == 0) ? Wz : (w == 1) ? Wr : Wh;
  *(bf16x8*)(dst + (long)w * 262144 + n * 512 + k8) = cvt8(W + (long)n * 1024 + 512 + k8);
  if (i < 256) ctr[i] = 0;
}

// ---------------- x-proj GEMM (128x128, 256 thr) + fused fc_w cvt blocks ----------------
__global__ __launch_bounds__(256) void xproj_k(
    const int* __restrict__ caps, const float* __restrict__ emb,
    const float* __restrict__ B0, const float* __restrict__ B1, const float* __restrict__ B2,
    const float* __restrict__ bias0, const float* __restrict__ bias1, const float* __restrict__ bias2,
    float* __restrict__ C, int gemm_blocks,
    const float* __restrict__ fcw_src, bf16* __restrict__ fcw_dst)
{
  __shared__ __align__(16) bf16 lA[128 * 32];
  __shared__ __align__(16) bf16 lB[128 * 32];
  const int tid = threadIdx.x;

  if ((int)blockIdx.x >= gemm_blocks) {   // fc_w f32->bf16 cvt
    long base = ((long)(blockIdx.x - gemm_blocks) * 256 + tid) * 8;
    const long stride = (long)128 * 256 * 8;
    for (long i = base; i < (long)V_SZ * H_SZ; i += stride)
      *(bf16x8*)(fcw_dst + i) = cvt8(fcw_src + i);
    return;
  }

  const int lane = tid & 63;
  const int l15  = lane & 15;
  const int kb8  = (lane >> 4) * 8;
  const int wid  = tid >> 6;
  const int wm   = wid >> 1, wn = wid & 1;
  const int wg   = blockIdx.x;
  const int mtile = wg % 16, ntile = wg / 16;
  const int m0 = mtile * 128, n0 = ntile * 128;

  int wsel = n0 >> 9;
  const float* Bv   = wsel == 0 ? B0 : wsel == 1 ? B1 : B2;
  const float* bias = wsel == 0 ? bias0 : wsel == 1 ? bias1 : bias2;
  int nb = n0 & 511;

  f32x4 acc[4][4] = {};

  for (int k0 = 0; k0 < 512; k0 += 32) {
    #pragma unroll
    for (int j = 0; j < 2; ++j) {
      int c = j * 256 + tid;
      int row = c >> 2;
      int kc = (c & 3) * 8;
      *(bf16x8*)&lA[row * 32 + kc] = cvt8(emb + (long)caps[m0 + row] * 512 + k0 + kc);
      *(bf16x8*)&lB[row * 32 + kc] = cvt8(Bv + (long)(nb + row) * 1024 + k0 + kc);
    }
    __syncthreads();
    bf16x8 af[4], bfr[4];
    #pragma unroll
    for (int mf = 0; mf < 4; ++mf)
      af[mf] = *(const bf16x8*)&lA[(wm * 64 + mf * 16 + l15) * 32 + kb8];
    #pragma unroll
    for (int nf = 0; nf < 4; ++nf)
      bfr[nf] = *(const bf16x8*)&lB[(wn * 64 + nf * 16 + l15) * 32 + kb8];
    #pragma unroll
    for (int mf = 0; mf < 4; ++mf)
      #pragma unroll
      for (int nf = 0; nf < 4; ++nf)
        acc[mf][nf] = __builtin_amdgcn_mfma_f32_16x16x32_bf16(af[mf], bfr[nf], acc[mf][nf], 0, 0, 0);
    __syncthreads();
  }

  #pragma unroll
  for (int mf = 0; mf < 4; ++mf)
    #pragma unroll
    for (int nf = 0; nf < 4; ++nf)
      #pragma unroll
      for (int r = 0; r < 4; ++r) {
        int row = m0 + wm * 64 + mf * 16 + (lane >> 4) * 4 + r;
        int lc  = wn * 64 + nf * 16 + l15;
        C[(long)row * 1536 + n0 + lc] = acc[mf][nf][r] + bias[nb + lc];
      }
}

// ---------------- FUSED: row-partitioned barrier-free GRU (blocks 0..7) +
//                  progress-gated logits workers (blocks 8..) ----------------
// Rec wg g owns batch rows g*4..g*4+3 and ALL 512 cols: zero cross-wg exchange.
// h and r*h live in LDS; weights streamed (L2-resident, 1.5MB/wg). Each wg
// publishes flag[g] = completed_steps/4 (sc0sc1, vmcnt-drained hs). Workers
// poll the 8 read-only flag lines (no RMW contention; rec never waits).
__global__ __launch_bounds__(512, 1) void fused_k(
    const float* __restrict__ X,
    const bf16* __restrict__ Wzh, const bf16* __restrict__ Wrh, const bf16* __restrict__ Whh,
    const float* __restrict__ feat,
    bf16* __restrict__ hs, int* __restrict__ ctr,
    const bf16* __restrict__ fcw16, const float* __restrict__ fcw_f32,
    const float* __restrict__ fc_b, float* __restrict__ out, int use_bf16B)
{
  __shared__ __align__(16) char smem[20480];
  const int tid  = threadIdx.x;                   // 0..511
  const int bid  = blockIdx.x;
  const int lane = tid & 63;
  const int l15  = lane & 15;

  if (bid < NWG_REC) {
    // ================= barrier-free recurrence: 4 rows x 512 cols =================
    bf16* h_lds  = (bf16*)smem;                   // [4][544] (1088B rows: <=2-way banks)
    bf16* rh_lds = (bf16*)(smem + 4352);          // [4][544]
    const int w   = tid >> 6;                     // wave 0..7 -> cols w*64..+63
    const int q   = lane >> 4;                    // k-chunk
    const int c0  = w * 64;
    const int b0  = bid * 4;                      // batch rows b0..b0+3

    const bf16* wzb = Wzh + (long)(c0 + l15) * 512 + q * 8;
    const bf16* wrb = Wrh + (long)(c0 + l15) * 512 + q * 8;
    const bf16* whb = Whh + (long)(c0 + l15) * 512 + q * 8;

    // init h in LDS + wave-private f32 h state (lanes 0-15 hold cols c0+nf*16+l15)
    for (int i = tid; i < 2048; i += 512) {
      int r = i >> 9, c = i & 511;
      h_lds[r * 544 + c] = (bf16)feat[(b0 + r) * 512 + c];
    }
    float hp[4][4];                               // [nf][r]
    if (lane < 16) {
      #pragma unroll
      for (int nf = 0; nf < 4; ++nf)
        #pragma unroll
        for (int r = 0; r < 4; ++r)
          hp[nf][r] = feat[(b0 + r) * 512 + c0 + nf * 16 + l15];
    }
    __syncthreads();

    int* flagp = ctr + bid * 32;
    const int abase = (l15 & 3) * 1088 + q * 16;  // A-frag byte base (row l15&3)
    float zf[4][4], xh[4][4];

    for (int t = 0; t < T_SZ; ++t) {
      // -------- phase 1: z (regs) + r -> rh_lds --------
      float xz[4][4], xr[4][4];
      if (lane < 16) {
        #pragma unroll
        for (int nf = 0; nf < 4; ++nf)
          #pragma unroll
          for (int r = 0; r < 4; ++r) {
            long xrow = (long)((b0 + r) * 64 + t) * 1536 + c0 + nf * 16 + l15;
            xz[nf][r] = X[xrow];
            xr[nf][r] = X[xrow + 512];
          }
      }
      f32x4 az[4] = {}, ar[4] = {};
      #pragma unroll
      for (int kk = 0; kk < 16; ++kk) {
        bf16x8 a = *(const bf16x8*)((char*)h_lds + abase + kk * 64);
        #pragma unroll
        for (int nf = 0; nf < 4; ++nf) {
          bf16x8 bz = *(const bf16x8*)(wzb + nf * 8192 + kk * 32);
          bf16x8 br = *(const bf16x8*)(wrb + nf * 8192 + kk * 32);
          az[nf] = __builtin_amdgcn_mfma_f32_16x16x32_bf16(a, bz, az[nf], 0, 0, 0);
          ar[nf] = __builtin_amdgcn_mfma_f32_16x16x32_bf16(a, br, ar[nf], 0, 0, 0);
        }
      }
      if (lane < 16) {
        #pragma unroll
        for (int nf = 0; nf < 4; ++nf)
          #pragma unroll
          for (int r = 0; r < 4; ++r) {
            float rv = sigmoidf_(ar[nf][r] + xr[nf][r]);
            rh_lds[r * 544 + c0 + nf * 16 + l15] = (bf16)(rv * hp[nf][r]);
            zf[nf][r] = sigmoidf_(az[nf][r] + xz[nf][r]);
          }
      }
      __syncthreads();

      // -------- phase 2: h_tilde + blend; h -> LDS; hs -> LLC --------
      if (lane < 16) {
        #pragma unroll
        for (int nf = 0; nf < 4; ++nf)
          #pragma unroll
          for (int r = 0; r < 4; ++r)
            xh[nf][r] = X[(long)((b0 + r) * 64 + t) * 1536 + 1024 + c0 + nf * 16 + l15];
      }
      f32x4 ah[4] = {};
      #pragma unroll
      for (int kk = 0; kk < 16; ++kk) {
        bf16x8 a = *(const bf16x8*)((char*)rh_lds + abase + kk * 64);
        #pragma unroll
        for (int nf = 0; nf < 4; ++nf) {
          bf16x8 bh = *(const bf16x8*)(whb + nf * 8192 + kk * 32);
          ah[nf] = __builtin_amdgcn_mfma_f32_16x16x32_bf16(a, bh, ah[nf], 0, 0, 0);
        }
      }
      if (lane < 16) {
        #pragma unroll
        for (int r = 0; r < 4; ++r) {
          bf16* hp_r = hs + (long)(t * 32 + b0 + r) * 512 + c0 + l15;  // t-major
          float v0, v1, v2, v3;
          {
            float ht;
            ht = tanhf(ah[0][r] + xh[0][r]); v0 = hp[0][r] + zf[0][r] * (ht - hp[0][r]);
            ht = tanhf(ah[1][r] + xh[1][r]); v1 = hp[1][r] + zf[1][r] * (ht - hp[1][r]);
            ht = tanhf(ah[2][r] + xh[2][r]); v2 = hp[2][r] + zf[2][r] * (ht - hp[2][r]);
            ht = tanhf(ah[3][r] + xh[3][r]); v3 = hp[3][r] + zf[3][r] * (ht - hp[3][r]);
            hp[0][r] = v0; hp[1][r] = v1; hp[2][r] = v2; hp[3][r] = v3;
          }
          h_lds[r * 544 + c0 + l15]      = (bf16)v0;
          h_lds[r * 544 + c0 + 16 + l15] = (bf16)v1;
          h_lds[r * 544 + c0 + 32 + l15] = (bf16)v2;
          h_lds[r * 544 + c0 + 48 + l15] = (bf16)v3;
          GST2(hp_r, "0", v0); GST2(hp_r, "32", v1); GST2(hp_r, "64", v2); GST2(hp_r, "96", v3);
        }
      }
      if ((t & 3) == 3) {
        WAITV;                       // all my hs stores at LLC
        __syncthreads();             // => all waves' stores at LLC
        if (tid == 0) {
          int fl = (t + 1) >> 2;
          asm volatile("global_store_dword %0, %1, off sc0 sc1" :: "v"(flagp), "v"(fl) : "memory");
        }
      } else {
        __syncthreads();             // h_lds write -> next-step read ordering
      }
    }
    return;
  }

  // ================= logits worker: 128x128 tile, 8 waves, flag-gated =================
  const int lwg   = bid - NWG_REC;
  const int mtile = lwg / NTILES;       // mtile-slow: early blocks take early timesteps
  const int ntile = lwg % NTILES;
  const int m0 = mtile * 128, n0 = ntile * 128;

  if (tid < 8) {                        // all 8 rec wgs must reach step 4*(mtile+1)
    const int tgt = mtile + 1;
    while (llc_poll(ctr + tid * 32) < tgt) __builtin_amdgcn_s_sleep(8);
  }
  __syncthreads();

  bf16* lA = (bf16*)smem;               // [128][40]  (80B rows: 2-way max)
  bf16* lB = (bf16*)(smem + 10240);     // [128][40]
  const int kb8  = (lane >> 4) * 8;
  const int wid  = tid >> 6;            // 0..7
  const int wm   = wid >> 1;            // 0..3 -> 32 rows each
  const int wn   = wid & 1;             // 0..1 -> 64 cols each
  const int arow = tid >> 2;
  const int akc  = (tid & 3) * 8;

  f32x4 acc[2][4] = {};

  for (int k0 = 0; k0 < 512; k0 += 32) {
    u32x4 av;
    GLD(av, hs + (long)(m0 + arow) * 512 + k0 + akc, "0");   // LLC-fresh
    bf16x8 bv;
    if (use_bf16B) bv = *(const bf16x8*)(fcw16 + (long)(n0 + arow) * 512 + k0 + akc);
    else           bv = cvt8(fcw_f32 + (long)(n0 + arow) * 512 + k0 + akc);
    WAITV;
    SCHEDB;
    *(u32x4*)&lA[arow * 40 + akc] = av;
    *(bf16x8*)&lB[arow * 40 + akc] = bv;
    __syncthreads();
    bf16x8 af[2], bfr[4];
    #pragma unroll
    for (int mf = 0; mf < 2; ++mf)
      af[mf] = *(const bf16x8*)&lA[(wm * 32 + mf * 16 + l15) * 40 + kb8];
    #pragma unroll
    for (int nf = 0; nf < 4; ++nf)
      bfr[nf] = *(const bf16x8*)&lB[(wn * 64 + nf * 16 + l15) * 40 + kb8];
    #pragma unroll
    for (int mf = 0; mf < 2; ++mf)
      #pragma unroll
      for (int nf = 0; nf < 4; ++nf)
        acc[mf][nf] = __builtin_amdgcn_mfma_f32_16x16x32_bf16(af[mf], bfr[nf], acc[mf][nf], 0, 0, 0);
    __syncthreads();
  }

  // epilogue: remap t-major row rr = t*32+b -> out row b*64+t
  #pragma unroll
  for (int mf = 0; mf < 2; ++mf)
    #pragma unroll
    for (int nf = 0; nf < 4; ++nf) {
      int col = n0 + wn * 64 + nf * 16 + l15;
      float bias_v = fc_b[col];
      #pragma unroll
      for (int r = 0; r < 4; ++r) {
        int rr = m0 + wm * 32 + mf * 16 + (lane >> 4) * 4 + r;
        int tt = rr >> 5, b = rr & 31;
        out[(long)(b * 64 + tt) * 32000 + col] = acc[mf][nf][r] + bias_v;
      }
    }
}

// ---------------- host ----------------
extern "C" void kernel_launch(void* const* d_in, const int* in_sizes, int n_in,
                              void* d_out, int out_size, void* d_ws, size_t ws_size,
                              hipStream_t stream) {
  const float* feat = (const float*)d_in[0];
  const int*   caps = (const int*)d_in[1];
  const float* emb  = (const float*)d_in[2];
  const float* Wz_w = (const float*)d_in[3];
  const float* Wz_b = (const float*)d_in[4];
  const float* Wr_w = (const float*)d_in[5];
  const float* Wr_b = (const float*)d_in[6];
  const float* Wh_w = (const float*)d_in[7];
  const float* Wh_b = (const float*)d_in[8];
  const float* fc_w = (const float*)d_in[9];
  const float* fc_b = (const float*)d_in[10];
  float* out = (float*)d_out;

  char* ws = (char*)d_ws;
  float* X_all = (float*)(ws + 0);              // 12,582,912
  bf16*  hs    = (bf16*) (ws + 12648448);       // 2,097,152 (t-major: row = t*32+b)
  bf16*  Whp   = (bf16*) (ws + 14745600);       // 1,572,864
  int*   ctr   = (int*)  (ws + 16318464);       // 1024 B flag area (8 wgs x 128B)
  bf16*  fcw16 = (bf16*) (ws + 16319488);       // 32,768,000 -> end 49,087,488
  const bool cvt_fc = (ws_size >= (size_t)49087500);

  prep_k<<<dim3(384), dim3(256), 0, stream>>>(feat, ctr, Wz_w, Wr_w, Wh_w, Whp);

  // x-projections (192 gemm blocks) + fc_w cvt (128 blocks)
  xproj_k<<<dim3(cvt_fc ? 320 : 192), dim3(256), 0, stream>>>(
      caps, emb, Wz_w, Wr_w, Wh_w, Wz_b, Wr_b, Wh_b, X_all, 192, fc_w, fcw16);

  // fused: 8 barrier-free recurrence wgs + 4000 flag-gated logits wgs
  fused_k<<<dim3(NWG_REC + MTILES * NTILES), dim3(512), 0, stream>>>(
      X_all, Whp, Whp + 262144, Whp + 524288, feat, hs, ctr,
      fcw16, fc_w, fc_b, out, cvt_fc ? 1 : 0);
}

// Round 13
// 650.903 us; speedup vs baseline: 4.6839x; 4.6839x over previous
//
#include <hip/hip_runtime.h>
#include <hip/hip_bf16.h>

typedef __bf16 bf16;
typedef __bf16 bf16x8 __attribute__((ext_vector_type(8)));
typedef float f32x4 __attribute__((ext_vector_type(4)));
typedef unsigned int u32x4 __attribute__((ext_vector_type(4)));

#define B_SZ 32
#define T_SZ 64
#define H_SZ 512
#define V_SZ 32000
#define NWG_REC 8
#define NTILES 250
#define MTILES 16

__device__ __forceinline__ float sigmoidf_(float v) { return 1.0f / (1.0f + expf(-v)); }

__device__ __forceinline__ bf16x8 cvt8(const float* __restrict__ p) {
  float4 a = *(const float4*)p;
  float4 b = *(const float4*)(p + 4);
  bf16x8 o;
  o[0] = (bf16)a.x; o[1] = (bf16)a.y; o[2] = (bf16)a.z; o[3] = (bf16)a.w;
  o[4] = (bf16)b.x; o[5] = (bf16)b.y; o[6] = (bf16)b.z; o[7] = (bf16)b.w;
  return o;
}

// ---- LLC-coherent primitives (bypass L1/L2 via sc0 sc1) ----
#define GLD(dst, base, off) \
  asm volatile("global_load_dwordx4 %0, %1, off offset:" off " sc0 sc1" \
               : "=v"(dst) : "v"(base))
#define GST2(base, off, val) do { \
  unsigned int w_ = (unsigned int)__builtin_bit_cast(unsigned short, (bf16)(val)); \
  asm volatile("global_store_short %0, %1, off offset:" off " sc0 sc1" \
               :: "v"(base), "v"(w_) : "memory"); \
} while (0)
#define WAITV  asm volatile("s_waitcnt vmcnt(0)" ::: "memory")
#define SCHEDB __builtin_amdgcn_sched_barrier(0)

__device__ __forceinline__ int llc_poll(const int* p) {
  int r;
  asm volatile("global_load_dword %0, %1, off sc0 sc1\n\ts_waitcnt vmcnt(0)"
               : "=v"(r) : "v"(p) : "memory");
  return r;
}

// ---------------- prep: h0 init, flags, Wz/Wr/Wh h-part extract+cvt ----------------
__global__ void prep_k(const float* __restrict__ feat, bf16* __restrict__ h_g,
                       int* __restrict__ ctr,
                       const float* __restrict__ Wz, const float* __restrict__ Wr,
                       const float* __restrict__ Wh, bf16* __restrict__ dst) {
  int i = blockIdx.x * blockDim.x + threadIdx.x;   // 98304 threads
  int w = i >> 15;
  int rem = i & 32767;
  int n = rem >> 6;
  int k8 = (rem & 63) * 8;
  const float* W = (w == 0) ? Wz : (w == 1) ? Wr : Wh;
  *(bf16x8*)(dst + (long)w * 262144 + n * 512 + k8) = cvt8(W + (long)n * 1024 + 512 + k8);
  if (i < B_SZ * H_SZ) h_g[i] = (bf16)feat[i];
  if (i < 128) ctr[i] = 0;
}

// ---------------- x-proj GEMM (128x128, 256 thr) + fused fc_w cvt blocks ----------------
__global__ __launch_bounds__(256) void xproj_k(
    const int* __restrict__ caps, const float* __restrict__ emb,
    const float* __restrict__ B0, const float* __restrict__ B1, const float* __restrict__ B2,
    const float* __restrict__ bias0, const float* __restrict__ bias1, const float* __restrict__ bias2,
    float* __restrict__ C, int gemm_blocks,
    const float* __restrict__ fcw_src, bf16* __restrict__ fcw_dst)
{
  __shared__ __align__(16) bf16 lA[128 * 32];
  __shared__ __align__(16) bf16 lB[128 * 32];
  const int tid = threadIdx.x;

  if ((int)blockIdx.x >= gemm_blocks) {   // fc_w f32->bf16 cvt
    long base = ((long)(blockIdx.x - gemm_blocks) * 256 + tid) * 8;
    const long stride = (long)128 * 256 * 8;
    for (long i = base; i < (long)V_SZ * H_SZ; i += stride)
      *(bf16x8*)(fcw_dst + i) = cvt8(fcw_src + i);
    return;
  }

  const int lane = tid & 63;
  const int l15  = lane & 15;
  const int kb8  = (lane >> 4) * 8;
  const int wid  = tid >> 6;
  const int wm   = wid >> 1, wn = wid & 1;
  const int wg   = blockIdx.x;
  const int mtile = wg % 16, ntile = wg / 16;
  const int m0 = mtile * 128, n0 = ntile * 128;

  int wsel = n0 >> 9;
  const float* Bv   = wsel == 0 ? B0 : wsel == 1 ? B1 : B2;
  const float* bias = wsel == 0 ? bias0 : wsel == 1 ? bias1 : bias2;
  int nb = n0 & 511;

  f32x4 acc[4][4] = {};

  for (int k0 = 0; k0 < 512; k0 += 32) {
    #pragma unroll
    for (int j = 0; j < 2; ++j) {
      int c = j * 256 + tid;
      int row = c >> 2;
      int kc = (c & 3) * 8;
      *(bf16x8*)&lA[row * 32 + kc] = cvt8(emb + (long)caps[m0 + row] * 512 + k0 + kc);
      *(bf16x8*)&lB[row * 32 + kc] = cvt8(Bv + (long)(nb + row) * 1024 + k0 + kc);
    }
    __syncthreads();
    bf16x8 af[4], bfr[4];
    #pragma unroll
    for (int mf = 0; mf < 4; ++mf)
      af[mf] = *(const bf16x8*)&lA[(wm * 64 + mf * 16 + l15) * 32 + kb8];
    #pragma unroll
    for (int nf = 0; nf < 4; ++nf)
      bfr[nf] = *(const bf16x8*)&lB[(wn * 64 + nf * 16 + l15) * 32 + kb8];
    #pragma unroll
    for (int mf = 0; mf < 4; ++mf)
      #pragma unroll
      for (int nf = 0; nf < 4; ++nf)
        acc[mf][nf] = __builtin_amdgcn_mfma_f32_16x16x32_bf16(af[mf], bfr[nf], acc[mf][nf], 0, 0, 0);
    __syncthreads();
  }

  #pragma unroll
  for (int mf = 0; mf < 4; ++mf)
    #pragma unroll
    for (int nf = 0; nf < 4; ++nf)
      #pragma unroll
      for (int r = 0; r < 4; ++r) {
        int row = m0 + wm * 64 + mf * 16 + (lane >> 4) * 4 + r;
        int lc  = wn * 64 + nf * 16 + l15;
        C[(long)row * 1536 + n0 + lc] = acc[mf][nf][r] + bias[nb + lc];
      }
}

// ---------------- FUSED: R4 recurrence (blocks 0..7) + gated logits workers ----------------
// ctr[0]  : rec barrier counter (touched ONLY by the 8 rec wgs; RMW line stays private)
// ctr[64] : read-only progress flag, published by rec wg 0 after each P2 barrier
//           completes (=> all hs stores for steps <= epoch/2 are LLC-visible).
// hs is t-major: row = t*32 + b.
__global__ __launch_bounds__(512, 2) void fused_k(
    const float* __restrict__ X,
    const bf16* __restrict__ Wzh, const bf16* __restrict__ Wrh, const bf16* __restrict__ Whh,
    const float* __restrict__ feat,
    bf16* __restrict__ h_g, bf16* __restrict__ rh_g,
    bf16* __restrict__ hs, int* __restrict__ ctr,
    const bf16* __restrict__ fcw16, const float* __restrict__ fcw_f32,
    const float* __restrict__ fc_b, float* __restrict__ out, int use_bf16B)
{
  __shared__ __align__(16) char smem[20480];
  const int tid  = threadIdx.x;                   // 0..511
  const int bid  = blockIdx.x;
  const int lane = tid & 63;
  const int l15  = lane & 15;
  int* prog = ctr + 64;

  if (bid < NWG_REC) {
    // ================= R4 recurrence (512 us proven) =================
    char* ldsb = smem;
    const int u    = bid * 8 + (tid >> 6);        // wave 0..63
    const int kb   = (lane >> 4) * 8;
    const int rq   = (lane >> 4) * 4;
    const int b0   = (u >> 5) * 16;
    const int gcol = (u & 31) * 16 + l15;

    u32x4 Bz[16], Br[16], Bh[16];
    #pragma unroll
    for (int kk = 0; kk < 16; ++kk) {
      Bz[kk] = *(const u32x4*)(Wzh + (long)gcol * 512 + kk * 32 + kb);
      Br[kk] = *(const u32x4*)(Wrh + (long)gcol * 512 + kk * 32 + kb);
      Bh[kk] = *(const u32x4*)(Whh + (long)gcol * 512 + kk * 32 + kb);
    }
    #pragma unroll
    for (int kk = 0; kk < 16; ++kk)
      asm volatile("" : "+v"(Bz[kk]), "+v"(Br[kk]), "+v"(Bh[kk]));

    float hprev[4];
    #pragma unroll
    for (int r = 0; r < 4; ++r) hprev[r] = feat[(b0 + rq + r) * 512 + gcol];

    const float* xb = X + (long)(b0 + rq) * 64 * 1536 + gcol;
    float xz[4], xr[4];
    #pragma unroll
    for (int r = 0; r < 4; ++r) {
      xz[r] = xb[r * 98304];
      xr[r] = xb[r * 98304 + 512];
    }

    const int srow0 = tid >> 6;
    const int soff0 = (tid * 16) ^ ((srow0 & 7) << 4);
    const int soff1 = (8192 + tid * 16) ^ ((srow0 & 7) << 4);
    const int fbase = (l15 * 1024 + (lane >> 4) * 16) ^ ((l15 & 7) << 4);

    bf16* rhst = rh_g + (b0 + rq) * 512 + gcol;
    bf16* hst  = h_g  + (b0 + rq) * 512 + gcol;

    int epoch = 0;
    for (int t = 0; t < T_SZ; ++t) {
      // ---- phase 1: stage h -> LDS; z (regs) + r -> rh ----
      {
        const bf16* src = h_g + b0 * 512;
        u32x4 v0, v1;
        GLD(v0, src + tid * 8, "0");
        GLD(v1, src + 4096 + tid * 8, "0");
        WAITV;
        SCHEDB;
        *(u32x4*)(ldsb + soff0) = v0;
        *(u32x4*)(ldsb + soff1) = v1;
      }
      __syncthreads();
      f32x4 ze = {}, re = {};
      #pragma unroll
      for (int kk = 0; kk < 16; ++kk) {
        bf16x8 a = *(const bf16x8*)(ldsb + (fbase ^ (kk * 64)));
        ze = __builtin_amdgcn_mfma_f32_16x16x32_bf16(a, __builtin_bit_cast(bf16x8, Bz[kk]), ze, 0, 0, 0);
        re = __builtin_amdgcn_mfma_f32_16x16x32_bf16(a, __builtin_bit_cast(bf16x8, Br[kk]), re, 0, 0, 0);
      }
      float xh[4];
      #pragma unroll
      for (int r = 0; r < 4; ++r) xh[r] = xb[r * 98304 + t * 1536 + 1024];
      f32x4 zf;
      {
        float r0 = sigmoidf_(re[0] + xr[0]) * hprev[0];
        float r1 = sigmoidf_(re[1] + xr[1]) * hprev[1];
        float r2 = sigmoidf_(re[2] + xr[2]) * hprev[2];
        float r3 = sigmoidf_(re[3] + xr[3]) * hprev[3];
        GST2(rhst, "0", r0); GST2(rhst, "1024", r1); GST2(rhst, "2048", r2); GST2(rhst, "3072", r3);
        #pragma unroll
        for (int r = 0; r < 4; ++r) zf[r] = sigmoidf_(ze[r] + xz[r]);
      }
      ++epoch;
      asm volatile("s_waitcnt vmcnt(0) lgkmcnt(0)" ::: "memory");
      __syncthreads();
      if (tid == 0) {
        __hip_atomic_fetch_add(ctr, 1, __ATOMIC_RELAXED, __HIP_MEMORY_SCOPE_AGENT);
        while (__hip_atomic_load(ctr, __ATOMIC_RELAXED, __HIP_MEMORY_SCOPE_AGENT) < NWG_REC * epoch)
          __builtin_amdgcn_s_sleep(1);
      }
      __syncthreads();

      // ---- phase 2: stage rh -> LDS; h_tilde + blend; h + hs(t-major) -> LLC ----
      {
        const bf16* src = rh_g + b0 * 512;
        u32x4 v0, v1;
        GLD(v0, src + tid * 8, "0");
        GLD(v1, src + 4096 + tid * 8, "0");
        WAITV;
        SCHEDB;
        *(u32x4*)(ldsb + soff0) = v0;
        *(u32x4*)(ldsb + soff1) = v1;
      }
      __syncthreads();
      f32x4 he = {};
      #pragma unroll
      for (int kk = 0; kk < 16; ++kk) {
        bf16x8 a = *(const bf16x8*)(ldsb + (fbase ^ (kk * 64)));
        he = __builtin_amdgcn_mfma_f32_16x16x32_bf16(a, __builtin_bit_cast(bf16x8, Bh[kk]), he, 0, 0, 0);
      }
      if (t + 1 < T_SZ) {
        #pragma unroll
        for (int r = 0; r < 4; ++r) {
          xz[r] = xb[r * 98304 + (t + 1) * 1536];
          xr[r] = xb[r * 98304 + (t + 1) * 1536 + 512];
        }
      }
      bf16* ph = hs + (long)(t * 32 + b0 + rq) * 512 + gcol;  // t-major
      #pragma unroll
      for (int r = 0; r < 4; ++r) {
        float ht = tanhf(he[r] + xh[r]);
        float hn = hprev[r] + zf[r] * (ht - hprev[r]);        // (1-z)h + z*ht
        hprev[r] = hn;
      }
      GST2(hst, "0", hprev[0]); GST2(hst, "1024", hprev[1]);
      GST2(hst, "2048", hprev[2]); GST2(hst, "3072", hprev[3]);
      GST2(ph, "0", hprev[0]); GST2(ph, "1024", hprev[1]);
      GST2(ph, "2048", hprev[2]); GST2(ph, "3072", hprev[3]);
      ++epoch;
      asm volatile("s_waitcnt vmcnt(0) lgkmcnt(0)" ::: "memory");
      __syncthreads();
      if (tid == 0) {
        __hip_atomic_fetch_add(ctr, 1, __ATOMIC_RELAXED, __HIP_MEMORY_SCOPE_AGENT);
        while (__hip_atomic_load(ctr, __ATOMIC_RELAXED, __HIP_MEMORY_SCOPE_AGENT) < NWG_REC * epoch)
          __builtin_amdgcn_s_sleep(1);
        if (bid == 0) {   // publish progress on a separate read-only line
          int e = epoch;
          asm volatile("global_store_dword %0, %1, off sc0 sc1" :: "v"(prog), "v"(e) : "memory");
        }
      }
      __syncthreads();
    }
    return;
  }

  // ================= logits worker: 128x128 tile, 8 waves, flag-gated =================
  const int lwg   = bid - NWG_REC;
  const int mtile = lwg / NTILES;       // mtile-slow: early blocks take early timesteps
  const int ntile = lwg % NTILES;
  const int m0 = mtile * 128, n0 = ntile * 128;

  if (tid == 0) {
    const int tgt = 8 * (mtile + 1);    // epoch after P2 of step 4*mtile+3
    while (llc_poll(prog) < tgt) __builtin_amdgcn_s_sleep(32);
  }
  __syncthreads();

  bf16* lA = (bf16*)smem;               // [128][40] (80B rows: <=2-way banks)
  bf16* lB = (bf16*)(smem + 10240);     // [128][40]
  const int kb8  = (lane >> 4) * 8;
  const int wid  = tid >> 6;            // 0..7
  const int wm   = wid >> 1;            // 0..3 -> 32 rows each
  const int wn   = wid & 1;             // 0..1 -> 64 cols each
  const int arow = tid >> 2;
  const int akc  = (tid & 3) * 8;

  f32x4 acc[2][4] = {};

  for (int k0 = 0; k0 < 512; k0 += 32) {
    u32x4 av;
    GLD(av, hs + (long)(m0 + arow) * 512 + k0 + akc, "0");   // LLC-fresh
    bf16x8 bv;
    if (use_bf16B) bv = *(const bf16x8*)(fcw16 + (long)(n0 + arow) * 512 + k0 + akc);
    else           bv = cvt8(fcw_f32 + (long)(n0 + arow) * 512 + k0 + akc);
    WAITV;
    SCHEDB;
    *(u32x4*)&lA[arow * 40 + akc] = av;
    *(bf16x8*)&lB[arow * 40 + akc] = bv;
    __syncthreads();
    bf16x8 af[2], bfr[4];
    #pragma unroll
    for (int mf = 0; mf < 2; ++mf)
      af[mf] = *(const bf16x8*)&lA[(wm * 32 + mf * 16 + l15) * 40 + kb8];
    #pragma unroll
    for (int nf = 0; nf < 4; ++nf)
      bfr[nf] = *(const bf16x8*)&lB[(wn * 64 + nf * 16 + l15) * 40 + kb8];
    #pragma unroll
    for (int mf = 0; mf < 2; ++mf)
      #pragma unroll
      for (int nf = 0; nf < 4; ++nf)
        acc[mf][nf] = __builtin_amdgcn_mfma_f32_16x16x32_bf16(af[mf], bfr[nf], acc[mf][nf], 0, 0, 0);
    __syncthreads();
  }

  // epilogue: remap t-major row rr = t*32+b -> out row b*64+t
  #pragma unroll
  for (int mf = 0; mf < 2; ++mf)
    #pragma unroll
    for (int nf = 0; nf < 4; ++nf) {
      int col = n0 + wn * 64 + nf * 16 + l15;
      float bias_v = fc_b[col];
      #pragma unroll
      for (int r = 0; r < 4; ++r) {
        int rr = m0 + wm * 32 + mf * 16 + (lane >> 4) * 4 + r;
        int tt = rr >> 5, b = rr & 31;
        out[(long)(b * 64 + tt) * 32000 + col] = acc[mf][nf][r] + bias_v;
      }
    }
}

// ---------------- host ----------------
extern "C" void kernel_launch(void* const* d_in, const int* in_sizes, int n_in,
                              void* d_out, int out_size, void* d_ws, size_t ws_size,
                              hipStream_t stream) {
  const float* feat = (const float*)d_in[0];
  const int*   caps = (const int*)d_in[1];
  const float* emb  = (const float*)d_in[2];
  const float* Wz_w = (const float*)d_in[3];
  const float* Wz_b = (const float*)d_in[4];
  const float* Wr_w = (const float*)d_in[5];
  const float* Wr_b = (const float*)d_in[6];
  const float* Wh_w = (const float*)d_in[7];
  const float* Wh_b = (const float*)d_in[8];
  const float* fc_w = (const float*)d_in[9];
  const float* fc_b = (const float*)d_in[10];
  float* out = (float*)d_out;

  char* ws = (char*)d_ws;
  float* X_all = (float*)(ws + 0);              // 12,582,912
  bf16*  h_g   = (bf16*) (ws + 12582912);       // 32,768
  bf16*  rh_g  = (bf16*) (ws + 12615680);       // 32,768
  bf16*  hs    = (bf16*) (ws + 12648448);       // 2,097,152 (t-major: row = t*32+b)
  bf16*  Whp   = (bf16*) (ws + 14745600);       // 1,572,864
  int*   ctr   = (int*)  (ws + 16318464);       // 512 B flag area
  bf16*  fcw16 = (bf16*) (ws + 16318976);       // 32,768,000 -> end 49,086,976
  const bool cvt_fc = (ws_size >= (size_t)49087000);

  prep_k<<<dim3(384), dim3(256), 0, stream>>>(feat, h_g, ctr, Wz_w, Wr_w, Wh_w, Whp);

  // x-projections (192 gemm blocks) + fc_w cvt (128 blocks)
  xproj_k<<<dim3(cvt_fc ? 320 : 192), dim3(256), 0, stream>>>(
      caps, emb, Wz_w, Wr_w, Wh_w, Wz_b, Wr_b, Wh_b, X_all, 192, fc_w, fcw16);

  // fused: 8 recurrence wgs + 4000 progress-gated logits wgs
  fused_k<<<dim3(NWG_REC + MTILES * NTILES), dim3(512), 0, stream>>>(
      X_all, Whp, Whp + 262144, Whp + 524288, feat, h_g, rh_g, hs, ctr,
      fcw16, fc_w, fc_b, out, cvt_fc ? 1 : 0);
}

// Round 15
// 646.799 us; speedup vs baseline: 4.7137x; 1.0063x over previous
//
#include <hip/hip_runtime.h>
#include <hip/hip_bf16.h>

typedef __bf16 bf16;
typedef __bf16 bf16x8 __attribute__((ext_vector_type(8)));
typedef float f32x4 __attribute__((ext_vector_type(4)));
typedef unsigned int u32x4 __attribute__((ext_vector_type(4)));

#define B_SZ 32
#define T_SZ 64
#define H_SZ 512
#define V_SZ 32000
#define NWG_REC 8
#define NTILES 250
#define MTILES 16

__device__ __forceinline__ float sigmoidf_(float v) { return 1.0f / (1.0f + expf(-v)); }

__device__ __forceinline__ bf16x8 cvt8(const float* __restrict__ p) {
  float4 a = *(const float4*)p;
  float4 b = *(const float4*)(p + 4);
  bf16x8 o;
  o[0] = (bf16)a.x; o[1] = (bf16)a.y; o[2] = (bf16)a.z; o[3] = (bf16)a.w;
  o[4] = (bf16)b.x; o[5] = (bf16)b.y; o[6] = (bf16)b.z; o[7] = (bf16)b.w;
  return o;
}

// ---- LLC-coherent primitives (bypass L1/L2 via sc0 sc1) ----
#define GLD(dst, base, off) \
  asm volatile("global_load_dwordx4 %0, %1, off offset:" off " sc0 sc1" \
               : "=v"(dst) : "v"(base))
#define LOADALL(af, base) do { \
  GLD(af[0],  base, "0");   GLD(af[1],  base, "64");  GLD(af[2],  base, "128"); GLD(af[3],  base, "192"); \
  GLD(af[4],  base, "256"); GLD(af[5],  base, "320"); GLD(af[6],  base, "384"); GLD(af[7],  base, "448"); \
  GLD(af[8],  base, "512"); GLD(af[9],  base, "576"); GLD(af[10], base, "640"); GLD(af[11], base, "704"); \
  GLD(af[12], base, "768"); GLD(af[13], base, "832"); GLD(af[14], base, "896"); GLD(af[15], base, "960"); \
} while (0)
#define GST2(base, off, val) do { \
  unsigned int w_ = (unsigned int)__builtin_bit_cast(unsigned short, (bf16)(val)); \
  asm volatile("global_store_short %0, %1, off offset:" off " sc0 sc1" \
               :: "v"(base), "v"(w_) : "memory"); \
} while (0)
#define WAITV  asm volatile("s_waitcnt vmcnt(0)" ::: "memory")
#define SCHEDB __builtin_amdgcn_sched_barrier(0)

__device__ __forceinline__ int llc_poll(const int* p) {
  int r;
  asm volatile("global_load_dword %0, %1, off sc0 sc1\n\ts_waitcnt vmcnt(0)"
               : "=v"(r) : "v"(p) : "memory");
  return r;
}

// ---------------- merged prologue: x-proj GEMM + fc_w cvt + prep (h0/flags/Wh extract) ----
__global__ __launch_bounds__(256) void xproj_k(
    const int* __restrict__ caps, const float* __restrict__ emb,
    const float* __restrict__ B0, const float* __restrict__ B1, const float* __restrict__ B2,
    const float* __restrict__ bias0, const float* __restrict__ bias1, const float* __restrict__ bias2,
    float* __restrict__ C, int gemm_blocks, int prep_start,
    const float* __restrict__ fcw_src, bf16* __restrict__ fcw_dst,
    const float* __restrict__ feat, bf16* __restrict__ h_g, int* __restrict__ ctr,
    bf16* __restrict__ whp_dst)
{
  __shared__ __align__(16) bf16 lA[128 * 32];
  __shared__ __align__(16) bf16 lB[128 * 32];
  const int tid = threadIdx.x;
  const int bidx = blockIdx.x;

  if (bidx >= prep_start) {               // prep: Wh-part extract + h0 + flags
    int i = (bidx - prep_start) * 256 + tid;   // 98304 threads
    int w = i >> 15;
    int rem = i & 32767;
    int n = rem >> 6;
    int k8 = (rem & 63) * 8;
    const float* W = (w == 0) ? B0 : (w == 1) ? B1 : B2;
    *(bf16x8*)(whp_dst + (long)w * 262144 + n * 512 + k8) = cvt8(W + (long)n * 1024 + 512 + k8);
    if (i < B_SZ * H_SZ) h_g[i] = (bf16)feat[i];
    if (i < 128) ctr[i] = 0;
    return;
  }

  if (bidx >= gemm_blocks) {              // fc_w f32->bf16 cvt
    long base = ((long)(bidx - gemm_blocks) * 256 + tid) * 8;
    const long stride = (long)128 * 256 * 8;
    for (long i = base; i < (long)V_SZ * H_SZ; i += stride)
      *(bf16x8*)(fcw_dst + i) = cvt8(fcw_src + i);
    return;
  }

  const int lane = tid & 63;
  const int l15  = lane & 15;
  const int kb8  = (lane >> 4) * 8;
  const int wid  = tid >> 6;
  const int wm   = wid >> 1, wn = wid & 1;
  const int mtile = bidx % 16, ntile = bidx / 16;
  const int m0 = mtile * 128, n0 = ntile * 128;

  int wsel = n0 >> 9;
  const float* Bv   = wsel == 0 ? B0 : wsel == 1 ? B1 : B2;
  const float* bias = wsel == 0 ? bias0 : wsel == 1 ? bias1 : bias2;
  int nb = n0 & 511;

  f32x4 acc[4][4] = {};

  for (int k0 = 0; k0 < 512; k0 += 32) {
    #pragma unroll
    for (int j = 0; j < 2; ++j) {
      int c = j * 256 + tid;
      int row = c >> 2;
      int kc = (c & 3) * 8;
      *(bf16x8*)&lA[row * 32 + kc] = cvt8(emb + (long)caps[m0 + row] * 512 + k0 + kc);
      *(bf16x8*)&lB[row * 32 + kc] = cvt8(Bv + (long)(nb + row) * 1024 + k0 + kc);
    }
    __syncthreads();
    bf16x8 af[4], bfr[4];
    #pragma unroll
    for (int mf = 0; mf < 4; ++mf)
      af[mf] = *(const bf16x8*)&lA[(wm * 64 + mf * 16 + l15) * 32 + kb8];
    #pragma unroll
    for (int nf = 0; nf < 4; ++nf)
      bfr[nf] = *(const bf16x8*)&lB[(wn * 64 + nf * 16 + l15) * 32 + kb8];
    #pragma unroll
    for (int mf = 0; mf < 4; ++mf)
      #pragma unroll
      for (int nf = 0; nf < 4; ++nf)
        acc[mf][nf] = __builtin_amdgcn_mfma_f32_16x16x32_bf16(af[mf], bfr[nf], acc[mf][nf], 0, 0, 0);
    __syncthreads();
  }

  #pragma unroll
  for (int mf = 0; mf < 4; ++mf)
    #pragma unroll
    for (int nf = 0; nf < 4; ++nf)
      #pragma unroll
      for (int r = 0; r < 4; ++r) {
        int row = m0 + wm * 64 + mf * 16 + (lane >> 4) * 4 + r;
        int lc  = wn * 64 + nf * 16 + l15;
        C[(long)row * 1536 + n0 + lc] = acc[mf][nf][r] + bias[nb + lc];
      }
}

// ---------------- FUSED: R4 recurrence (blocks 0..7) + gated logits workers ----------------
// launch_bounds (512,1): VGPR budget 256 -> Bz+Br (128) truly pinned via opaque asm;
// Bh streamed from L2 in phase 2 (latency overlaps MFMA chain).
// ctr[0]: rec barrier (RMW line private to 8 rec wgs). ctr[64]: read-only prog flag.
// hs is t-major: row = t*32 + b.
__global__ __launch_bounds__(512, 1) void fused_k(
    const float* __restrict__ X,
    const bf16* __restrict__ Wzh, const bf16* __restrict__ Wrh, const bf16* __restrict__ Whh,
    const float* __restrict__ feat,
    bf16* __restrict__ h_g, bf16* __restrict__ rh_g,
    bf16* __restrict__ hs, int* __restrict__ ctr,
    const bf16* __restrict__ fcw16, const float* __restrict__ fcw_f32,
    const float* __restrict__ fc_b, float* __restrict__ out, int use_bf16B)
{
  __shared__ __align__(16) char smem[20480];
  const int tid  = threadIdx.x;                   // 0..511
  const int bid  = blockIdx.x;
  const int lane = tid & 63;
  const int l15  = lane & 15;
  int* prog = ctr + 64;

  if (bid < NWG_REC) {
    // ================= R4 recurrence, spill-free weight pin =================
    char* ldsb = smem;
    const int u    = bid * 8 + (tid >> 6);        // wave 0..63
    const int kb   = (lane >> 4) * 8;
    const int rq   = (lane >> 4) * 4;
    const int b0   = (u >> 5) * 16;
    const int gcol = (u & 31) * 16 + l15;

    // pinned phase-1 weights: opaque asm loads (cannot be rematerialized; fit in 256)
    u32x4 Bz[16], Br[16];
    LOADALL(Bz, Wzh + (long)gcol * 512 + kb);
    LOADALL(Br, Wrh + (long)gcol * 512 + kb);
    WAITV;
    const bf16* whb = Whh + (long)gcol * 512 + kb;   // Bh streamed (L2-hot after step 0)

    float hprev[4];
    #pragma unroll
    for (int r = 0; r < 4; ++r) hprev[r] = feat[(b0 + rq + r) * 512 + gcol];

    const float* xb = X + (long)(b0 + rq) * 64 * 1536 + gcol;
    float xz[4], xr[4];
    #pragma unroll
    for (int r = 0; r < 4; ++r) {
      xz[r] = xb[r * 98304];
      xr[r] = xb[r * 98304 + 512];
    }

    const int srow0 = tid >> 6;
    const int soff0 = (tid * 16) ^ ((srow0 & 7) << 4);
    const int soff1 = (8192 + tid * 16) ^ ((srow0 & 7) << 4);
    const int fbase = (l15 * 1024 + (lane >> 4) * 16) ^ ((l15 & 7) << 4);

    bf16* rhst = rh_g + (b0 + rq) * 512 + gcol;
    bf16* hst  = h_g  + (b0 + rq) * 512 + gcol;

    int epoch = 0;
    for (int t = 0; t < T_SZ; ++t) {
      // ---- phase 1: stage h -> LDS; z (regs) + r -> rh ----
      {
        const bf16* src = h_g + b0 * 512;
        u32x4 v0, v1;
        GLD(v0, src + tid * 8, "0");
        GLD(v1, src + 4096 + tid * 8, "0");
        WAITV;
        SCHEDB;
        *(u32x4*)(ldsb + soff0) = v0;
        *(u32x4*)(ldsb + soff1) = v1;
      }
      __syncthreads();
      f32x4 ze = {}, re = {};
      #pragma unroll
      for (int kk = 0; kk < 16; ++kk) {
        bf16x8 a = *(const bf16x8*)(ldsb + (fbase ^ (kk * 64)));
        ze = __builtin_amdgcn_mfma_f32_16x16x32_bf16(a, __builtin_bit_cast(bf16x8, Bz[kk]), ze, 0, 0, 0);
        re = __builtin_amdgcn_mfma_f32_16x16x32_bf16(a, __builtin_bit_cast(bf16x8, Br[kk]), re, 0, 0, 0);
      }
      float xh[4];
      #pragma unroll
      for (int r = 0; r < 4; ++r) xh[r] = xb[r * 98304 + t * 1536 + 1024];
      f32x4 zf;
      {
        float r0 = sigmoidf_(re[0] + xr[0]) * hprev[0];
        float r1 = sigmoidf_(re[1] + xr[1]) * hprev[1];
        float r2 = sigmoidf_(re[2] + xr[2]) * hprev[2];
        float r3 = sigmoidf_(re[3] + xr[3]) * hprev[3];
        GST2(rhst, "0", r0); GST2(rhst, "1024", r1); GST2(rhst, "2048", r2); GST2(rhst, "3072", r3);
        #pragma unroll
        for (int r = 0; r < 4; ++r) zf[r] = sigmoidf_(ze[r] + xz[r]);
      }
      ++epoch;
      WAITV;
      __syncthreads();
      if (tid == 0) {
        __hip_atomic_fetch_add(ctr, 1, __ATOMIC_RELAXED, __HIP_MEMORY_SCOPE_AGENT);
        while (__hip_atomic_load(ctr, __ATOMIC_RELAXED, __HIP_MEMORY_SCOPE_AGENT) < NWG_REC * epoch)
          __builtin_amdgcn_s_sleep(1);
      }
      __syncthreads();

      // ---- phase 2: stage rh -> LDS; h_tilde (Bh streamed) + blend; h + hs -> LLC ----
      {
        const bf16* src = rh_g + b0 * 512;
        u32x4 v0, v1;
        GLD(v0, src + tid * 8, "0");
        GLD(v1, src + 4096 + tid * 8, "0");
        WAITV;
        SCHEDB;
        *(u32x4*)(ldsb + soff0) = v0;
        *(u32x4*)(ldsb + soff1) = v1;
      }
      __syncthreads();
      f32x4 he = {};
      #pragma unroll
      for (int kk = 0; kk < 16; ++kk) {
        bf16x8 a = *(const bf16x8*)(ldsb + (fbase ^ (kk * 64)));
        u32x4 bh = *(const u32x4*)(whb + kk * 32);   // streamed via L1/L2
        he = __builtin_amdgcn_mfma_f32_16x16x32_bf16(a, __builtin_bit_cast(bf16x8, bh), he, 0, 0, 0);
      }
      if (t + 1 < T_SZ) {
        #pragma unroll
        for (int r = 0; r < 4; ++r) {
          xz[r] = xb[r * 98304 + (t + 1) * 1536];
          xr[r] = xb[r * 98304 + (t + 1) * 1536 + 512];
        }
      }
      bf16* ph = hs + (long)(t * 32 + b0 + rq) * 512 + gcol;  // t-major
      #pragma unroll
      for (int r = 0; r < 4; ++r) {
        float ht = tanhf(he[r] + xh[r]);
        float hn = hprev[r] + zf[r] * (ht - hprev[r]);        // (1-z)h + z*ht
        hprev[r] = hn;
      }
      GST2(hst, "0", hprev[0]); GST2(hst, "1024", hprev[1]);
      GST2(hst, "2048", hprev[2]); GST2(hst, "3072", hprev[3]);
      GST2(ph, "0", hprev[0]); GST2(ph, "1024", hprev[1]);
      GST2(ph, "2048", hprev[2]); GST2(ph, "3072", hprev[3]);
      ++epoch;
      WAITV;
      __syncthreads();
      if (tid == 0) {
        __hip_atomic_fetch_add(ctr, 1, __ATOMIC_RELAXED, __HIP_MEMORY_SCOPE_AGENT);
        while (__hip_atomic_load(ctr, __ATOMIC_RELAXED, __HIP_MEMORY_SCOPE_AGENT) < NWG_REC * epoch)
          __builtin_amdgcn_s_sleep(1);
        if (bid == 0) {   // publish progress on a separate read-only line
          int e = epoch;
          asm volatile("global_store_dword %0, %1, off sc0 sc1" :: "v"(prog), "v"(e) : "memory");
        }
      }
      __syncthreads();
    }
    return;
  }

  // ================= logits worker: 128x128 tile, 8 waves, flag-gated =================
  const int lwg   = bid - NWG_REC;
  const int mtile = lwg / NTILES;       // mtile-slow: early blocks take early timesteps
  const int ntile = lwg % NTILES;
  const int m0 = mtile * 128, n0 = ntile * 128;

  if (tid == 0) {
    const int tgt = 8 * (mtile + 1);    // epoch after P2 of step 4*mtile+3
    while (llc_poll(prog) < tgt) __builtin_amdgcn_s_sleep(32);
  }
  __syncthreads();

  bf16* lA = (bf16*)smem;               // [128][40] (80B rows: <=2-way banks)
  bf16* lB = (bf16*)(smem + 10240);     // [128][40]
  const int kb8  = (lane >> 4) * 8;
  const int wid  = tid >> 6;            // 0..7
  const int wm   = wid >> 1;            // 0..3 -> 32 rows each
  const int wn   = wid & 1;             // 0..1 -> 64 cols each
  const int arow = tid >> 2;
  const int akc  = (tid & 3) * 8;

  f32x4 acc[2][4] = {};

  for (int k0 = 0; k0 < 512; k0 += 32) {
    u32x4 av;
    GLD(av, hs + (long)(m0 + arow) * 512 + k0 + akc, "0");   // LLC-fresh
    bf16x8 bv;
    if (use_bf16B) bv = *(const bf16x8*)(fcw16 + (long)(n0 + arow) * 512 + k0 + akc);
    else           bv = cvt8(fcw_f32 + (long)(n0 + arow) * 512 + k0 + akc);
    WAITV;
    SCHEDB;
    *(u32x4*)&lA[arow * 40 + akc] = av;
    *(bf16x8*)&lB[arow * 40 + akc] = bv;
    __syncthreads();
    bf16x8 af[2], bfr[4];
    #pragma unroll
    for (int mf = 0; mf < 2; ++mf)
      af[mf] = *(const bf16x8*)&lA[(wm * 32 + mf * 16 + l15) * 40 + kb8];
    #pragma unroll
    for (int nf = 0; nf < 4; ++nf)
      bfr[nf] = *(const bf16x8*)&lB[(wn * 64 + nf * 16 + l15) * 40 + kb8];
    #pragma unroll
    for (int mf = 0; mf < 2; ++mf)
      #pragma unroll
      for (int nf = 0; nf < 4; ++nf)
        acc[mf][nf] = __builtin_amdgcn_mfma_f32_16x16x32_bf16(af[mf], bfr[nf], acc[mf][nf], 0, 0, 0);
    __syncthreads();
  }

  // epilogue: remap t-major row rr = t*32+b -> out row b*64+t
  #pragma unroll
  for (int mf = 0; mf < 2; ++mf)
    #pragma unroll
    for (int nf = 0; nf < 4; ++nf) {
      int col = n0 + wn * 64 + nf * 16 + l15;
      float bias_v = fc_b[col];
      #pragma unroll
      for (int r = 0; r < 4; ++r) {
        int rr = m0 + wm * 32 + mf * 16 + (lane >> 4) * 4 + r;
        int tt = rr >> 5, b = rr & 31;
        out[(long)(b * 64 + tt) * 32000 + col] = acc[mf][nf][r] + bias_v;
      }
    }
}

// ---------------- host ----------------
extern "C" void kernel_launch(void* const* d_in, const int* in_sizes, int n_in,
                              void* d_out, int out_size, void* d_ws, size_t ws_size,
                              hipStream_t stream) {
  const float* feat = (const float*)d_in[0];
  const int*   caps = (const int*)d_in[1];
  const float* emb  = (const float*)d_in[2];
  const float* Wz_w = (const float*)d_in[3];
  const float* Wz_b = (const float*)d_in[4];
  const float* Wr_w = (const float*)d_in[5];
  const float* Wr_b = (const float*)d_in[6];
  const float* Wh_w = (const float*)d_in[7];
  const float* Wh_b = (const float*)d_in[8];
  const float* fc_w = (const float*)d_in[9];
  const float* fc_b = (const float*)d_in[10];
  float* out = (float*)d_out;

  char* ws = (char*)d_ws;
  float* X_all = (float*)(ws + 0);              // 12,582,912
  bf16*  h_g   = (bf16*) (ws + 12582912);       // 32,768
  bf16*  rh_g  = (bf16*) (ws + 12615680);       // 32,768
  bf16*  hs    = (bf16*) (ws + 12648448);       // 2,097,152 (t-major: row = t*32+b)
  bf16*  Whp   = (bf16*) (ws + 14745600);       // 1,572,864
  int*   ctr   = (int*)  (ws + 16318464);       // 512 B flag area
  bf16*  fcw16 = (bf16*) (ws + 16318976);       // 32,768,000 -> end 49,086,976
  const bool cvt_fc = (ws_size >= (size_t)49087000);

  // merged prologue: 192 gemm blocks + (cvt_fc ? 128 cvt : 0) + 384 prep blocks
  const int prep_start = cvt_fc ? 320 : 192;
  xproj_k<<<dim3(prep_start + 384), dim3(256), 0, stream>>>(
      caps, emb, Wz_w, Wr_w, Wh_w, Wz_b, Wr_b, Wh_b, X_all, 192, prep_start,
      fc_w, fcw16, feat, h_g, ctr, Whp);

  // fused: 8 recurrence wgs + 4000 progress-gated logits wgs
  fused_k<<<dim3(NWG_REC + MTILES * NTILES), dim3(512), 0, stream>>>(
      X_all, Whp, Whp + 262144, Whp + 524288, feat, h_g, rh_g, hs, ctr,
      fcw16, fc_w, fc_b, out, cvt_fc ? 1 : 0);
}